// Round 11
// baseline (271.139 us; speedup 1.0000x reference)
//
#include <hip/hip_runtime.h>

// VectorQuantiser forward, MI355X fp32.
// N=65536 tokens (16x64x64, channel dim 64 strided by 4096), K=1024 codes, D=64.
//
// Round 13. Round-10 lessons: SQ_LDS_BANK_CONFLICT=4194304 is the b-frag
// ds_read_b128 cost (unchanged when the cmU atomic was removed -> the RMW
// never conflicted; round-10's colmax rows were a 32KB LDS bloat for nothing).
// VALU diet landed (38->23%) but dur 95.5->91.2: k_mfma is LDS-pipe/latency
// bound (2048 b128 reads x ~16cyc x 2 blk/CU ~= 27us + 16 barrier drains,
// 2 indep MFMA chains/wave). This round:
//  - k_mfma: 32 tokens/wave (two tiles share every b-frag read), 256 blocks.
//    LDS reads per token halved, e-L2 traffic halved (128->64MB), barriers
//    halved, 4 indep MFMA chains/wave (a1A/a2A/a1B/a2B). colmax back to the
//    4KB cmU atomic (proven conflict-neutral) -> LDS 45KB. launch_bounds
//    (512,1): grid=256=1 block/CU, VGPR free to ~150 (no artificial cap --
//    round-5 lesson). cbm shrinks to [1024][256] (256-token col groups).
//  - k_tokens: 4-way channel split, 1024 blocks (was 1 blk/CU with a serial
//    64-iter gather chain). Loss partial-sum order changes only in double
//    (~1e-16 rel; final float unchanged; tolerance is 1.5e-5 regardless).
// All exact fp paths (norms/splits, 4-chain fmaf dots, key packing, ties,
// z_q ops, tail) verbatim from the passing code.

#define MARGIN 2e-4f
#define CERT   2e-4f

// ---- ws layout (bytes) ----
#define WS_ROW   0         // u64 wsrow[65536]
#define WS_COL   524288    // u64 wscol[1024]
#define WS_CNT   532480    // u32 counts[1024]
#define WS_LOSS  536576    // double loss_acc
#define WS_EN2   536592    // float en2[1024]
#define WS_LCNT  540688    // u32 lcnt
#define WS_ZN2   541696    // float zn2[65536]            (256KB)
#define WS_EBH   803840    // u16 ebf_hi[1024*64]         (128KB)
#define WS_EBL   934912    // u16 ebf_lo[1024*64]         (128KB)
#define WS_LIST  1065984   // u32 list[65536]             (256KB)
#define WS_CBM   1322112   // f32 colbm[1024][256]        (1MB)
#define WS_BYTES 2370688
#define WS_ZERO  540720    // memset range: row/col/cnt/loss/lcnt

typedef __attribute__((ext_vector_type(8))) short short8v;
typedef __attribute__((ext_vector_type(4))) float f32x4;

__device__ __forceinline__ unsigned int f32_ord(float x) {
    unsigned int b = __float_as_uint(x);
    return (b & 0x80000000u) ? ~b : (b | 0x80000000u);
}
__device__ __forceinline__ float ord_f32(unsigned int u) {  // exact inverse
    unsigned int b = (u & 0x80000000u) ? (u & 0x7FFFFFFFu) : ~u;
    return __uint_as_float(b);
}

__device__ __forceinline__ unsigned short f2bf(float f) {  // RNE fp32->bf16
    unsigned int u = __float_as_uint(f);
    return (unsigned short)((u + 0x7FFFu + ((u >> 16) & 1u)) >> 16);
}
__device__ __forceinline__ float bf2f(unsigned short h) {
    return __uint_as_float((unsigned int)h << 16);
}

// numpy pairwise sum of squares over 64 values (verbatim from passing code).
template <typename F>
__device__ __forceinline__ float np_pairwise64_sq(F get) {
    float r[8];
#pragma unroll
    for (int j = 0; j < 8; ++j) {
        float v = get(j);
        r[j] = __fmul_rn(v, v);
    }
#pragma unroll
    for (int i = 8; i < 64; i += 8) {
#pragma unroll
        for (int j = 0; j < 8; ++j) {
            float v = get(i + j);
            r[j] = __fadd_rn(r[j], __fmul_rn(v, v));
        }
    }
    return __fadd_rn(__fadd_rn(__fadd_rn(r[0], r[1]), __fadd_rn(r[2], r[3])),
                     __fadd_rn(__fadd_rn(r[4], r[5]), __fadd_rn(r[6], r[7])));
}

// ---- K0: norms + bf16 hi/lo splits (unchanged, validated 5x) ----
__global__ __launch_bounds__(256) void k_prep(
    const float* __restrict__ z, const float* __restrict__ emb,
    float* __restrict__ en2, float* __restrict__ zn2,
    unsigned int* __restrict__ zbh32, unsigned int* __restrict__ zbl32,
    unsigned int* __restrict__ ebh32, unsigned int* __restrict__ ebl32) {
    const int t = threadIdx.x;
    if (blockIdx.x < 1024) {
        const int n0  = blockIdx.x * 64;
        const int b   = n0 >> 12;
        const int hw0 = n0 & 4095;

        __shared__ float        zl[64][65];   // [ch][tok], pad 65
        __shared__ unsigned int oh[64][33];   // [tok][wd], pad 33
        __shared__ unsigned int ol[64][33];

#pragma unroll
        for (int it = 0; it < 16; ++it) {
            int idx = it * 256 + t;
            int c = idx >> 6, tok = idx & 63;
            zl[c][tok] = z[(size_t)b * 262144 + (size_t)c * 4096 + hw0 + tok];
        }
        __syncthreads();

        const int tk = t & 63, q = t >> 6;
        if (q == 0)
            zn2[n0 + tk] = np_pairwise64_sq([&](int i) { return zl[i][tk]; });

#pragma unroll
        for (int w8 = 0; w8 < 8; ++w8) {
            int wd = q * 8 + w8;
            float z0 = zl[2 * wd][tk], z1 = zl[2 * wd + 1][tk];
            unsigned short h0 = f2bf(z0), h1 = f2bf(z1);
            oh[tk][wd] = (unsigned int)h0 | ((unsigned int)h1 << 16);
            unsigned short l0 = f2bf(__fsub_rn(z0, bf2f(h0)));
            unsigned short l1 = f2bf(__fsub_rn(z1, bf2f(h1)));
            ol[tk][wd] = (unsigned int)l0 | ((unsigned int)l1 << 16);
        }
        __syncthreads();

#pragma unroll
        for (int it = 0; it < 8; ++it) {
            int idx = it * 256 + t;
            int tok = idx >> 5, wd = idx & 31;
            zbh32[(size_t)(n0 + tok) * 32 + wd] = oh[tok][wd];
            zbl32[(size_t)(n0 + tok) * 32 + wd] = ol[tok][wd];
        }
    } else {
        const int k = (blockIdx.x - 1024) * 256 + t;
        const float* a = emb + (size_t)k * 64;
        float ar[64];
#pragma unroll
        for (int i = 0; i < 64; ++i) ar[i] = a[i];
        en2[k] = np_pairwise64_sq([&](int i) { return ar[i]; });
#pragma unroll
        for (int wd = 0; wd < 32; ++wd) {
            float e0 = ar[2 * wd], e1 = ar[2 * wd + 1];
            unsigned short h0 = f2bf(e0), h1 = f2bf(e1);
            ebh32[k * 32 + wd] = (unsigned int)h0 | ((unsigned int)h1 << 16);
            unsigned short l0 = f2bf(__fsub_rn(e0, bf2f(h0)));
            unsigned short l1 = f2bf(__fsub_rn(e1, bf2f(h1)));
            ebl32[k * 32 + wd] = (unsigned int)l0 | ((unsigned int)l1 << 16);
        }
    }
}

// ---- K1: s~ via bf16 MFMA, 32 tokens/wave (2 tiles share b-frags) ----
// grid 256 x 512 (8 waves). Wave w: tile A = tokens n0+w*16.., tile B =
// tile A + 128. All 1024 codes in 16 LDS-dbuf groups of 64.
__global__ __launch_bounds__(512, 1) void k_mfma(
    const unsigned short* __restrict__ zbh, const unsigned short* __restrict__ zbl,
    const unsigned short* __restrict__ ebh, const unsigned short* __restrict__ ebl,
    const float* __restrict__ zn2, const float* __restrict__ en2,
    float* __restrict__ cbm, unsigned long long* __restrict__ wsrow,
    unsigned int* __restrict__ lcnt, unsigned int* __restrict__ list) {
    const int t = threadIdx.x, l = t & 63, w = t >> 6;
    const int n0 = blockIdx.x * 256;
    const int tw = n0 + w * 16;          // tile A base; tile B = tw + 128
    const int lm = l & 15, kg = l >> 4;

    __shared__ __align__(16) unsigned int eh[2][64 * 36];
    __shared__ __align__(16) unsigned int el[2][64 * 36];
    __shared__ float        en2l[1024];
    __shared__ unsigned int cmU[1024];   // column max as f32_ord (atomicMax)

    for (int i = t; i < 1024; i += 512) { en2l[i] = en2[i]; cmU[i] = 0u; }

    const uint4* EH4 = reinterpret_cast<const uint4*>(ebh);
    const uint4* EL4 = reinterpret_cast<const uint4*>(ebl);
    const int scode = t >> 3, swd = (t & 7) * 4;

    {   // stage group 0
        uint4 hv = EH4[t], lv = EL4[t];
        *reinterpret_cast<uint4*>(&eh[0][scode * 36 + swd]) = hv;
        *reinterpret_cast<uint4*>(&el[0][scode * 36 + swd]) = lv;
    }

    const int tokA = tw + lm, tokB = tokA + 128;
    const short8v ahA0 = *reinterpret_cast<const short8v*>(zbh + tokA * 64 + kg * 8);
    const short8v ahA1 = *reinterpret_cast<const short8v*>(zbh + tokA * 64 + 32 + kg * 8);
    const short8v alA0 = *reinterpret_cast<const short8v*>(zbl + tokA * 64 + kg * 8);
    const short8v alA1 = *reinterpret_cast<const short8v*>(zbl + tokA * 64 + 32 + kg * 8);
    const short8v ahB0 = *reinterpret_cast<const short8v*>(zbh + tokB * 64 + kg * 8);
    const short8v ahB1 = *reinterpret_cast<const short8v*>(zbh + tokB * 64 + 32 + kg * 8);
    const short8v alB0 = *reinterpret_cast<const short8v*>(zbl + tokB * 64 + kg * 8);
    const short8v alB1 = *reinterpret_cast<const short8v*>(zbl + tokB * 64 + 32 + kg * 8);

    float nznA[4], nznB[4];
    {
        const float4 za = *reinterpret_cast<const float4*>(zn2 + tw + kg * 4);
        const float4 zb = *reinterpret_cast<const float4*>(zn2 + tw + 128 + kg * 4);
        nznA[0] = -za.x; nznA[1] = -za.y; nznA[2] = -za.z; nznA[3] = -za.w;
        nznB[0] = -zb.x; nznB[1] = -zb.y; nznB[2] = -zb.z; nznB[3] = -zb.w;
    }
    float v1A[4] = {-3.4e38f, -3.4e38f, -3.4e38f, -3.4e38f};
    float v2A[4] = {-3.4e38f, -3.4e38f, -3.4e38f, -3.4e38f};
    int   c1A[4] = {0, 0, 0, 0};
    float v1B[4] = {-3.4e38f, -3.4e38f, -3.4e38f, -3.4e38f};
    float v2B[4] = {-3.4e38f, -3.4e38f, -3.4e38f, -3.4e38f};
    int   c1B[4] = {0, 0, 0, 0};

    __syncthreads();

    for (int g = 0; g < 16; ++g) {
        const int buf = g & 1;
        const bool pf = (g < 15);
        uint4 hv, lv;
        if (pf) {   // issue next group's loads early; write AFTER compute
            hv = EH4[(g + 1) * 512 + t];
            lv = EL4[(g + 1) * 512 + t];
        }

#pragma unroll
        for (int sc = 0; sc < 4; ++sc) {
            const int cl = sc * 16 + lm;
            const short8v bh0 = *reinterpret_cast<const short8v*>(&eh[buf][cl * 36 + kg * 4]);
            const short8v bh1 = *reinterpret_cast<const short8v*>(&eh[buf][cl * 36 + 16 + kg * 4]);
            const short8v bl0 = *reinterpret_cast<const short8v*>(&el[buf][cl * 36 + kg * 4]);
            const short8v bl1 = *reinterpret_cast<const short8v*>(&el[buf][cl * 36 + 16 + kg * 4]);

            f32x4 a1A = {0.f, 0.f, 0.f, 0.f};
            f32x4 a2A = {0.f, 0.f, 0.f, 0.f};
            f32x4 a1B = {0.f, 0.f, 0.f, 0.f};
            f32x4 a2B = {0.f, 0.f, 0.f, 0.f};
            __builtin_amdgcn_s_setprio(1);
            a1A = __builtin_amdgcn_mfma_f32_16x16x32_bf16(ahA0, bh0, a1A, 0, 0, 0);
            a1B = __builtin_amdgcn_mfma_f32_16x16x32_bf16(ahB0, bh0, a1B, 0, 0, 0);
            a1A = __builtin_amdgcn_mfma_f32_16x16x32_bf16(ahA1, bh1, a1A, 0, 0, 0);
            a1B = __builtin_amdgcn_mfma_f32_16x16x32_bf16(ahB1, bh1, a1B, 0, 0, 0);
            a2A = __builtin_amdgcn_mfma_f32_16x16x32_bf16(ahA0, bl0, a2A, 0, 0, 0);
            a2B = __builtin_amdgcn_mfma_f32_16x16x32_bf16(ahB0, bl0, a2B, 0, 0, 0);
            a2A = __builtin_amdgcn_mfma_f32_16x16x32_bf16(ahA1, bl1, a2A, 0, 0, 0);
            a2B = __builtin_amdgcn_mfma_f32_16x16x32_bf16(ahB1, bl1, a2B, 0, 0, 0);
            a2A = __builtin_amdgcn_mfma_f32_16x16x32_bf16(alA0, bh0, a2A, 0, 0, 0);
            a2B = __builtin_amdgcn_mfma_f32_16x16x32_bf16(alB0, bh0, a2B, 0, 0, 0);
            a2A = __builtin_amdgcn_mfma_f32_16x16x32_bf16(alA1, bh1, a2A, 0, 0, 0);
            a2B = __builtin_amdgcn_mfma_f32_16x16x32_bf16(alB1, bh1, a2B, 0, 0, 0);
            __builtin_amdgcn_s_setprio(0);

            const int code = g * 64 + cl;
            const float en2v = en2l[code];
            float cm = -3.4e38f;
#pragma unroll
            for (int j = 0; j < 4; ++j) {
                float accA  = __fadd_rn(a1A[j], a2A[j]);
                float baseA = __fsub_rn(nznA[j], en2v);
                float sA    = fmaf(2.0f, accA, baseA);
                bool gtA = sA > v1A[j];
                v2A[j] = fmaxf(fminf(sA, v1A[j]), v2A[j]);
                v1A[j] = fmaxf(v1A[j], sA);
                c1A[j] = gtA ? code : c1A[j];
                cm = fmaxf(cm, sA);

                float accB  = __fadd_rn(a1B[j], a2B[j]);
                float baseB = __fsub_rn(nznB[j], en2v);
                float sB    = fmaf(2.0f, accB, baseB);
                bool gtB = sB > v1B[j];
                v2B[j] = fmaxf(fminf(sB, v1B[j]), v2B[j]);
                v1B[j] = fmaxf(v1B[j], sB);
                c1B[j] = gtB ? code : c1B[j];
                cm = fmaxf(cm, sB);
            }
            cm = fmaxf(cm, __shfl_xor(cm, 16, 64));
            cm = fmaxf(cm, __shfl_xor(cm, 32, 64));
            if (l < 16) atomicMax(&cmU[code], f32_ord(cm));
        }

        if (pf) {
            *reinterpret_cast<uint4*>(&eh[buf ^ 1][scode * 36 + swd]) = hv;
            *reinterpret_cast<uint4*>(&el[buf ^ 1][scode * 36 + swd]) = lv;
        }
        __syncthreads();
    }

    // ---- row finalize: merge top-2 across the 16 lm-lanes, certify ----
#pragma unroll
    for (int tile = 0; tile < 2; ++tile) {
        const int tbase = tw + tile * 128;
#pragma unroll
        for (int j = 0; j < 4; ++j) {
            float fv1 = tile ? v1B[j] : v1A[j];
            float fv2 = tile ? v2B[j] : v2A[j];
            int   fc1 = tile ? c1B[j] : c1A[j];
            unsigned long long key =
                ((unsigned long long)f32_ord(fv1) << 32) |
                (unsigned long long)(unsigned int)(~(unsigned int)fc1);
            float w2 = fv2;
#pragma unroll
            for (int m = 1; m < 16; m <<= 1) {
                unsigned long long ok = __shfl_xor(key, m, 64);
                float ov2 = __shfl_xor(w2, m, 64);
                unsigned long long lk = (key < ok) ? key : ok;   // losing top1
                float lv2 = ord_f32((unsigned int)(lk >> 32));
                w2 = fmaxf(fmaxf(w2, ov2), lv2);
                key = (key > ok) ? key : ok;                     // ties: smaller c
            }
            if (lm == 0) {
                const int tn = tbase + kg * 4 + j;
                float v1m = ord_f32((unsigned int)(key >> 32));
                if (__fsub_rn(v1m, w2) > CERT) {
                    wsrow[tn] = key;  // certified: provably exact argmax index
                } else {
                    unsigned int p = atomicAdd(lcnt, 1u);
                    list[p] = (unsigned int)tn;
                }
            }
        }
    }

    for (int code = t; code < 1024; code += 512)
        cbm[(size_t)code * 256 + blockIdx.x] = ord_f32(cmU[code]);
}

// ---- K2: merged exact rescore (col: blocks 0..1023; row: 1024..2047) ----
// Bodies verbatim; col groups are now 256 tokens (256 k_mfma blocks).
__global__ __launch_bounds__(256) void k_rescore(
    const float* __restrict__ z, const float* __restrict__ emb,
    const float* __restrict__ zn2, const float* __restrict__ en2,
    const float* __restrict__ cbm,
    const unsigned int* __restrict__ list, const unsigned int* __restrict__ lcnt,
    unsigned long long* __restrict__ wscol,
    unsigned long long* __restrict__ wsrow) {
    const int t = threadIdx.x;
    if (blockIdx.x < 1024) {
        // -- column rescore: block per code --
        const int k = blockIdx.x;
        __shared__ float red[256];
        __shared__ int   hlist[256];
        __shared__ int   hcnt;
        float a = cbm[(size_t)k * 256 + t];
        red[t] = a;
        if (t == 0) hcnt = 0;
        __syncthreads();
        for (int st = 128; st; st >>= 1) {
            if (t < st) red[t] = fmaxf(red[t], red[t + st]);
            __syncthreads();
        }
        const float thr = red[0] - MARGIN;
        if (a >= thr) { int p = atomicAdd(&hcnt, 1); hlist[p] = t; }
        __syncthreads();
        const int hc = hcnt;
        const float en2k = en2[k];
        const float4* ek = reinterpret_cast<const float4*>(emb + (size_t)k * 64);

        for (int h = 0; h < hc; ++h) {
            const int g = hlist[h];
            const int n = g * 256 + t;
            const int b = n >> 12, hw = n & 4095;
            const float* zp = z + (size_t)b * 262144 + hw;
            float c0 = 0.f, c1 = 0.f, c2 = 0.f, c3 = 0.f;
#pragma unroll
            for (int j = 0; j < 16; ++j) {
                float4 e = ek[j];
                c0 = fmaf(e.x, zp[(size_t)(4 * j + 0) * 4096], c0);
                c1 = fmaf(e.y, zp[(size_t)(4 * j + 1) * 4096], c1);
                c2 = fmaf(e.z, zp[(size_t)(4 * j + 2) * 4096], c2);
                c3 = fmaf(e.w, zp[(size_t)(4 * j + 3) * 4096], c3);
            }
            float dot = (c0 + c1) + (c2 + c3);
            float d = __fadd_rn(__fsub_rn(-zn2[n], en2k), 2.0f * dot);
            unsigned long long key =
                ((unsigned long long)f32_ord(d) << 32) |
                (unsigned long long)(unsigned int)(~(unsigned int)n);
#pragma unroll
            for (int m = 1; m < 64; m <<= 1) {
                unsigned long long o = __shfl_xor(key, m, 64);
                if (o > key) key = o;    // ties: larger key = smaller n
            }
            if ((t & 63) == 0) atomicMax(&wscol[k], key);
        }
    } else {
        // -- row rescore for uncertified tokens --
        const int bid2 = blockIdx.x - 1024;
        const int k0 = (bid2 >> 6) * 64;     // 16 partitions of 64 codes
        const unsigned int cnt = *lcnt;
        const float4* E4 = reinterpret_cast<const float4*>(emb);
        for (unsigned int i = (unsigned int)(bid2 & 63) * 256 + t; i < cnt;
             i += 64 * 256) {
            const int n = (int)list[i];
            const int b = n >> 12, hw = n & 4095;
            const float* zp = z + (size_t)b * 262144 + hw;
            const float nz = -zn2[n];
            unsigned long long best = 0ull;
            for (int kk = 0; kk < 64; ++kk) {
                const int k = k0 + kk;               // wave-uniform -> s_load
                const float4* ek = E4 + (size_t)k * 16;
                float c0 = 0.f, c1 = 0.f, c2 = 0.f, c3 = 0.f;
#pragma unroll
                for (int j = 0; j < 16; ++j) {
                    float4 e = ek[j];
                    c0 = fmaf(e.x, zp[(size_t)(4 * j + 0) * 4096], c0);
                    c1 = fmaf(e.y, zp[(size_t)(4 * j + 1) * 4096], c1);
                    c2 = fmaf(e.z, zp[(size_t)(4 * j + 2) * 4096], c2);
                    c3 = fmaf(e.w, zp[(size_t)(4 * j + 3) * 4096], c3);
                }
                float dot = (c0 + c1) + (c2 + c3);
                float d = __fadd_rn(__fsub_rn(nz, en2[k]), 2.0f * dot);
                unsigned long long key =
                    ((unsigned long long)f32_ord(d) << 32) |
                    (unsigned long long)(unsigned int)(~(unsigned int)k);
                if (key > best) best = key;   // ties: larger key = smaller k
            }
            atomicMax(&wsrow[n], best);
        }
    }
}

// ---- K3: per-token outputs, 4-way channel split (1024 blocks) ----
// thread (lane=token, q=channel quarter). z/out accesses stay coalesced;
// per-token loss = ((q0+q1)+(q2+q3)) of per-quarter double partials (order
// differs from the 64-seq chain only at double precision ~1e-16 rel).
__global__ __launch_bounds__(256) void k_tokens(
    const float* __restrict__ z, const float* __restrict__ emb,
    const unsigned long long* __restrict__ wsrow,
    unsigned int* __restrict__ counts, double* __restrict__ loss_acc,
    float* __restrict__ out_zq, float* __restrict__ out_idx) {
    const int t    = threadIdx.x;
    const int lane = t & 63;
    const int q    = t >> 6;
    const int n    = blockIdx.x * 64 + lane;
    const int b    = n >> 12;
    const int hw   = n & 4095;

    unsigned long long key = wsrow[n];
    int idx = (int)(~(unsigned int)(key & 0xFFFFFFFFull));
    if (q == 0) {
        out_idx[n] = (float)idx;
        atomicAdd(&counts[idx], 1u);
    }

    const float* zp = z + (size_t)b * 262144 + hw;
    float*       op = out_zq + (size_t)b * 262144 + hw;
    const float* ep = emb + (size_t)idx * 64;

    double ls = 0.0;
#pragma unroll
    for (int c = q * 16; c < q * 16 + 16; ++c) {
        float zc   = zp[(size_t)c * 4096];
        float eq   = ep[c];
        float diff = __fsub_rn(eq, zc);              // fl(z_q - zc)
        float sq   = __fmul_rn(diff, diff);
        ls += (double)sq;
        op[(size_t)c * 4096] = __fadd_rn(zc, diff);  // zc + fl(z_q - zc)
    }

    __shared__ double sred[256];
    sred[q * 64 + lane] = ls;
    __syncthreads();
    if (t < 64) {
        sred[t] = (sred[t] + sred[64 + t]) + (sred[128 + t] + sred[192 + t]);
    }
    __syncthreads();
    for (int st = 32; st; st >>= 1) {
        if (t < st) sred[t] += sred[t + st];
        __syncthreads();
    }
    if (t == 0) atomicAdd(loss_acc, sred[0]);
}

// ---- K4: tail — new embedding + scalars (unchanged) ----
__global__ __launch_bounds__(1024) void k_tail(
    const float* __restrict__ z, const float* __restrict__ emb,
    const float* __restrict__ embed_prob,
    const unsigned long long* __restrict__ wscol,
    const unsigned int* __restrict__ counts,
    const double* __restrict__ loss_acc,
    float* __restrict__ out_newemb, float* __restrict__ out_loss,
    float* __restrict__ out_perp, float* __restrict__ out_prob) {
    const int k = blockIdx.x * 16 + (threadIdx.x >> 6);
    const int c = threadIdx.x & 63;

    float avg  = (float)counts[k] * (1.0f / 65536.0f);
    float pnew = __fadd_rn(__fmul_rn(embed_prob[k], 0.99f),
                           __fmul_rn(0.01f, avg));
    float tt = __fdiv_rn(__fmul_rn(__fmul_rn(pnew, 1024.0f), 10.0f), 0.01f);
    float dk = expf(__fsub_rn(-tt, 1e-3f));
    float omd = __fsub_rn(1.0f, dk);

    unsigned long long ck = wscol[k];
    int cn  = (int)(~(unsigned int)(ck & 0xFFFFFFFFull));
    int cb  = cn >> 12;
    int chw = cn & 4095;

    float rf = z[(size_t)cb * 262144 + (size_t)c * 4096 + chw];
    float e  = emb[(size_t)k * 64 + c];
    out_newemb[(size_t)k * 64 + c] =
        __fadd_rn(__fmul_rn(e, omd), __fmul_rn(rf, dk));

    if (blockIdx.x == 0) {
        const int q = threadIdx.x;

        float avg2  = (float)counts[q] * (1.0f / 65536.0f);
        float pnew2 = __fadd_rn(__fmul_rn(embed_prob[q], 0.99f),
                                __fmul_rn(0.01f, avg2));
        out_prob[q] = pnew2;

        float term = __fmul_rn(avg2, logf(__fadd_rn(avg2, 1e-10f)));
        __shared__ double red[1024];
        red[q] = (double)term;
        __syncthreads();
        for (int st = 512; st; st >>= 1) {
            if (q < st) red[q] += red[q + st];
            __syncthreads();
        }
        if (q == 0) {
            float s32 = (float)red[0];
            out_perp[0] = expf(-s32);
            double lm = loss_acc[0] / 4194304.0;
            float  m  = (float)lm;
            out_loss[0] = __fadd_rn(__fmul_rn(0.25f, m), m);  // BETA*m + m
        }
    }
}

extern "C" void kernel_launch(void* const* d_in, const int* in_sizes, int n_in,
                              void* d_out, int out_size, void* d_ws, size_t ws_size,
                              hipStream_t stream) {
    const float* z    = (const float*)d_in[0];   // 16*64*64*64
    const float* emb  = (const float*)d_in[1];   // 1024*64
    const float* prob = (const float*)d_in[2];   // 1024

    float* out        = (float*)d_out;
    float* out_zq     = out;                 // 4194304 floats (16.777 MB)
    float* out_loss   = out + 4194304;
    float* out_perp   = out + 4194305;
    float* out_newemb = out + 4194306;
    float* out_prob   = out + 4259842;
    float* out_idx    = out + 4260866;

    char* ws = (char*)d_ws;
    unsigned long long* wsrow = (unsigned long long*)(ws + WS_ROW);
    unsigned long long* wscol = (unsigned long long*)(ws + WS_COL);
    unsigned int*       cnts  = (unsigned int*)(ws + WS_CNT);
    double*             lacc  = (double*)(ws + WS_LOSS);
    float*              en2   = (float*)(ws + WS_EN2);
    unsigned int*       lcnt  = (unsigned int*)(ws + WS_LCNT);
    float*              zn2   = (float*)(ws + WS_ZN2);
    unsigned short*     ebh   = (unsigned short*)(ws + WS_EBH);
    unsigned short*     ebl   = (unsigned short*)(ws + WS_EBL);
    unsigned int*       list  = (unsigned int*)(ws + WS_LIST);
    float*              cbm   = (float*)(ws + WS_CBM);

    // out_zq doubles as scratch before k_tokens rewrites it:
    //   zbf_hi u16[4.2M] @ bytes [0, 8388608)
    //   zbf_lo u16[4.2M] @ bytes [8388608, 16777216)
    unsigned short* zbh = (unsigned short*)out_zq;
    unsigned short* zbl = (unsigned short*)((char*)out_zq + 8388608);

    hipMemsetAsync(d_ws, 0, WS_ZERO, stream);

    hipLaunchKernelGGL(k_prep, dim3(1028), dim3(256), 0, stream,
                       z, emb, en2, zn2,
                       (unsigned int*)zbh, (unsigned int*)zbl,
                       (unsigned int*)ebh, (unsigned int*)ebl);
    hipLaunchKernelGGL(k_mfma, dim3(256), dim3(512), 0, stream,
                       zbh, zbl, ebh, ebl, zn2, en2, cbm, wsrow, lcnt, list);
    hipLaunchKernelGGL(k_rescore, dim3(2048), dim3(256), 0, stream,
                       z, emb, zn2, en2, cbm, list, lcnt, wscol, wsrow);
    hipLaunchKernelGGL(k_tokens, dim3(1024), dim3(256), 0, stream,
                       z, emb, wsrow, cnts, lacc, out_zq, out_idx);
    hipLaunchKernelGGL(k_tail, dim3(64), dim3(1024), 0, stream,
                       z, emb, prob, wscol, cnts, lacc,
                       out_newemb, out_loss, out_perp, out_prob);
}

// Round 12
// 257.892 us; speedup vs baseline: 1.0514x; 1.0514x over previous
//
#include <hip/hip_runtime.h>

// VectorQuantiser forward, MI355X fp32.
// N=65536 tokens (16x64x64, channel dim 64 strided by 4096), K=1024 codes, D=64.
//
// Round 14. Round-13 lesson: 32-tok/wave at 1 blk/CU regressed (Occ 33->20%,
// 2 waves/SIMD; TLP loss > ILP gain) -> revert k_mfma to the PROVEN round-12
// shape (512 blocks, 16 tok/wave, 2 blk/CU, 91.2us). Structural cut this
// round: k_prep's z-part is fused into k_mfma's prologue -- each block only
// touches tokens n0..n0+127, so the bf16 hi/lo split + zn2 for them is
// computed in-block from global z (LDS transpose; VERBATIM split/norm
// formulas -> bit-identical values). Deletes a 1024-block launch + 33MB of
// zbh/zbl scratch round-trip; k_prep shrinks to 4 e-only blocks. Smem is
// carved by hand: the 33KB z-staging tile overlays the e-dbuf region
// (disjoint in time, 4 prologue barriers).
// All exact fp paths (norms/splits, 4-chain fmaf dots, key packing, ties,
// z_q ops, tail) verbatim from the passing code. absmax must stay
// 1.525879e-05 exactly.

#define MARGIN 2e-4f
#define CERT   2e-4f

// ---- ws layout (bytes) ----
#define WS_ROW   0         // u64 wsrow[65536]
#define WS_COL   524288    // u64 wscol[1024]
#define WS_CNT   532480    // u32 counts[1024]
#define WS_LOSS  536576    // double loss_acc
#define WS_EN2   536592    // float en2[1024]
#define WS_LCNT  540688    // u32 lcnt
#define WS_ZN2   541696    // float zn2[65536]            (256KB)
#define WS_EBH   803840    // u16 ebf_hi[1024*64]         (128KB)
#define WS_EBL   934912    // u16 ebf_lo[1024*64]         (128KB)
#define WS_LIST  1065984   // u32 list[65536]             (256KB)
#define WS_CBM   1328128   // f32 colbm[1024][512]        (2MB)
#define WS_BYTES 3425280
#define WS_ZERO  540720    // memset range: row/col/cnt/loss/lcnt

typedef __attribute__((ext_vector_type(8))) short short8v;
typedef __attribute__((ext_vector_type(4))) float f32x4;

__device__ __forceinline__ unsigned int f32_ord(float x) {
    unsigned int b = __float_as_uint(x);
    return (b & 0x80000000u) ? ~b : (b | 0x80000000u);
}
__device__ __forceinline__ float ord_f32(unsigned int u) {  // exact inverse
    unsigned int b = (u & 0x80000000u) ? (u & 0x7FFFFFFFu) : ~u;
    return __uint_as_float(b);
}

__device__ __forceinline__ unsigned short f2bf(float f) {  // RNE fp32->bf16
    unsigned int u = __float_as_uint(f);
    return (unsigned short)((u + 0x7FFFu + ((u >> 16) & 1u)) >> 16);
}
__device__ __forceinline__ float bf2f(unsigned short h) {
    return __uint_as_float((unsigned int)h << 16);
}

// numpy pairwise sum of squares over 64 values (verbatim from passing code).
template <typename F>
__device__ __forceinline__ float np_pairwise64_sq(F get) {
    float r[8];
#pragma unroll
    for (int j = 0; j < 8; ++j) {
        float v = get(j);
        r[j] = __fmul_rn(v, v);
    }
#pragma unroll
    for (int i = 8; i < 64; i += 8) {
#pragma unroll
        for (int j = 0; j < 8; ++j) {
            float v = get(i + j);
            r[j] = __fadd_rn(r[j], __fmul_rn(v, v));
        }
    }
    return __fadd_rn(__fadd_rn(__fadd_rn(r[0], r[1]), __fadd_rn(r[2], r[3])),
                     __fadd_rn(__fadd_rn(r[4], r[5]), __fadd_rn(r[6], r[7])));
}

// ---- K0: e-only prep: en2 + codebook bf16 hi/lo splits (4 blocks) ----
__global__ __launch_bounds__(256) void k_prep(
    const float* __restrict__ emb, float* __restrict__ en2,
    unsigned int* __restrict__ ebh32, unsigned int* __restrict__ ebl32) {
    const int t = threadIdx.x;
    const int k = blockIdx.x * 256 + t;
    const float* a = emb + (size_t)k * 64;
    float ar[64];
#pragma unroll
    for (int i = 0; i < 64; ++i) ar[i] = a[i];
    en2[k] = np_pairwise64_sq([&](int i) { return ar[i]; });
#pragma unroll
    for (int wd = 0; wd < 32; ++wd) {
        float e0 = ar[2 * wd], e1 = ar[2 * wd + 1];
        unsigned short h0 = f2bf(e0), h1 = f2bf(e1);
        ebh32[k * 32 + wd] = (unsigned int)h0 | ((unsigned int)h1 << 16);
        unsigned short l0 = f2bf(__fsub_rn(e0, bf2f(h0)));
        unsigned short l1 = f2bf(__fsub_rn(e1, bf2f(h1)));
        ebl32[k * 32 + wd] = (unsigned int)l0 | ((unsigned int)l1 << 16);
    }
}

// ---- K1: fused z-prep + s~ via bf16 MFMA + top-2 certification ----
// grid 512 x 512 (8 waves). Wave w: tokens tw..tw+15, all 1024 codes in 16
// LDS-dbuf groups of 64. Prologue: LDS-transpose this block's 128 tokens,
// compute zn2 (verbatim chain) + bf16 hi/lo frags in-register.
// Smem carve (45056 B):
//   [0,18432)      u32 eh[2][64*36]      | prologue: f32 zl[64][129] (33024 B)
//   [18432,36864)  u32 el[2][64*36]      |   overlays eh+el (disjoint in time)
//   [36864,40960)  f32 en2l[1024]        | prologue: f32 zntmp[128]
//   [40960,45056)  u32 cmU[1024]
__global__ __launch_bounds__(512, 2) void k_mfma(
    const float* __restrict__ z,
    const unsigned short* __restrict__ ebh, const unsigned short* __restrict__ ebl,
    float* __restrict__ zn2, const float* __restrict__ en2,
    float* __restrict__ cbm, unsigned long long* __restrict__ wsrow,
    unsigned int* __restrict__ lcnt, unsigned int* __restrict__ list) {
    const int t = threadIdx.x, l = t & 63, w = t >> 6;
    const int n0 = blockIdx.x * 128;
    const int tw = n0 + w * 16;
    const int lm = l & 15, kg = l >> 4;
    const int b   = n0 >> 12;
    const int hw0 = n0 & 4095;

    __shared__ __align__(16) unsigned char smem[45056];
    unsigned int* eh   = (unsigned int*)(smem);            // [2][64*36]
    unsigned int* el   = (unsigned int*)(smem + 18432);    // [2][64*36]
    float*        en2l = (float*)(smem + 36864);           // [1024]
    unsigned int* cmU  = (unsigned int*)(smem + 40960);    // [1024]
    float*        zl   = (float*)(smem);                   // [64][129] prologue
    float*        zntmp= (float*)(smem + 36864);           // [128]     prologue

    // --- prologue phase 1: global z -> LDS transpose (coalesced) ---
    const float* zsrc = z + (size_t)b * 262144 + hw0;
#pragma unroll
    for (int it = 0; it < 16; ++it) {
        int idx = it * 512 + t;
        int c = idx >> 7, tok = idx & 127;
        zl[c * 129 + tok] = zsrc[(size_t)c * 4096 + tok];
    }
    __syncthreads();

    // --- prologue phase 2: zn2 (verbatim chain) + fragment assembly ---
    if (t < 128) {
        float v = np_pairwise64_sq([&](int i) { return zl[i * 129 + t]; });
        zn2[n0 + t] = v;
        zntmp[t] = v;
    }
    const int tokA = w * 16 + lm;   // block-local token of this thread's A-frag
    short8v ah0, ah1, al0, al1;
#pragma unroll
    for (int j = 0; j < 8; ++j) {
        float z0 = zl[(kg * 8 + j) * 129 + tokA];
        float z1 = zl[(32 + kg * 8 + j) * 129 + tokA];
        unsigned short h0 = f2bf(z0);
        unsigned short h1 = f2bf(z1);
        ah0[j] = (short)h0;
        ah1[j] = (short)h1;
        al0[j] = (short)f2bf(__fsub_rn(z0, bf2f(h0)));
        al1[j] = (short)f2bf(__fsub_rn(z1, bf2f(h1)));
    }
    __syncthreads();

    // --- prologue phase 3: read zn2 for this thread's C/D rows ---
    float nzn2[4];
#pragma unroll
    for (int j = 0; j < 4; ++j) nzn2[j] = -zntmp[w * 16 + kg * 4 + j];
    __syncthreads();

    // --- prologue phase 4: init en2l/cmU, stage e group 0 ---
    for (int i = t; i < 1024; i += 512) { en2l[i] = en2[i]; cmU[i] = 0u; }
    const uint4* EH4 = reinterpret_cast<const uint4*>(ebh);
    const uint4* EL4 = reinterpret_cast<const uint4*>(ebl);
    const int scode = t >> 3, swd = (t & 7) * 4;
    {
        uint4 hv = EH4[t], lv = EL4[t];
        *reinterpret_cast<uint4*>(&eh[0 * 2304 + scode * 36 + swd]) = hv;
        *reinterpret_cast<uint4*>(&el[0 * 2304 + scode * 36 + swd]) = lv;
    }

    float v1[4] = {-3.4e38f, -3.4e38f, -3.4e38f, -3.4e38f};
    float v2[4] = {-3.4e38f, -3.4e38f, -3.4e38f, -3.4e38f};
    int   c1[4] = {0, 0, 0, 0};

    __syncthreads();

    for (int g = 0; g < 16; ++g) {
        const int buf = g & 1;
        const bool pf = (g < 15);
        uint4 hv, lv;
        if (pf) {   // issue next group's loads early; write AFTER compute
            hv = EH4[(g + 1) * 512 + t];
            lv = EL4[(g + 1) * 512 + t];
        }

#pragma unroll
        for (int sc = 0; sc < 4; ++sc) {
            const int cl = sc * 16 + lm;
            const short8v bh0 = *reinterpret_cast<const short8v*>(&eh[buf * 2304 + cl * 36 + kg * 4]);
            const short8v bh1 = *reinterpret_cast<const short8v*>(&eh[buf * 2304 + cl * 36 + 16 + kg * 4]);
            const short8v bl0 = *reinterpret_cast<const short8v*>(&el[buf * 2304 + cl * 36 + kg * 4]);
            const short8v bl1 = *reinterpret_cast<const short8v*>(&el[buf * 2304 + cl * 36 + 16 + kg * 4]);

            f32x4 a1 = {0.f, 0.f, 0.f, 0.f};
            f32x4 a2 = {0.f, 0.f, 0.f, 0.f};
            __builtin_amdgcn_s_setprio(1);
            a1 = __builtin_amdgcn_mfma_f32_16x16x32_bf16(ah0, bh0, a1, 0, 0, 0);
            a1 = __builtin_amdgcn_mfma_f32_16x16x32_bf16(ah1, bh1, a1, 0, 0, 0);
            a2 = __builtin_amdgcn_mfma_f32_16x16x32_bf16(ah0, bl0, a2, 0, 0, 0);
            a2 = __builtin_amdgcn_mfma_f32_16x16x32_bf16(ah1, bl1, a2, 0, 0, 0);
            a2 = __builtin_amdgcn_mfma_f32_16x16x32_bf16(al0, bh0, a2, 0, 0, 0);
            a2 = __builtin_amdgcn_mfma_f32_16x16x32_bf16(al1, bh1, a2, 0, 0, 0);
            __builtin_amdgcn_s_setprio(0);

            const int code = g * 64 + cl;
            const float en2v = en2l[code];
            float cm = -3.4e38f;
#pragma unroll
            for (int j = 0; j < 4; ++j) {
                float acc  = __fadd_rn(a1[j], a2[j]);
                float base = __fsub_rn(nzn2[j], en2v);
                float s    = fmaf(2.0f, acc, base);
                // top-2, min/max form (identical values to the branchy version)
                bool gt = s > v1[j];
                v2[j] = fmaxf(fminf(s, v1[j]), v2[j]);
                v1[j] = fmaxf(v1[j], s);
                c1[j] = gt ? code : c1[j];
                cm = fmaxf(cm, s);
            }
            cm = fmaxf(cm, __shfl_xor(cm, 16, 64));
            cm = fmaxf(cm, __shfl_xor(cm, 32, 64));
            if (l < 16) atomicMax(&cmU[code], f32_ord(cm));
        }

        if (pf) {
            *reinterpret_cast<uint4*>(&eh[(buf ^ 1) * 2304 + scode * 36 + swd]) = hv;
            *reinterpret_cast<uint4*>(&el[(buf ^ 1) * 2304 + scode * 36 + swd]) = lv;
        }
        __syncthreads();
    }

    // ---- row finalize: merge top-2 across the 16 lm-lanes, certify ----
#pragma unroll
    for (int j = 0; j < 4; ++j) {
        unsigned long long key =
            ((unsigned long long)f32_ord(v1[j]) << 32) |
            (unsigned long long)(unsigned int)(~(unsigned int)c1[j]);
        float w2 = v2[j];
#pragma unroll
        for (int m = 1; m < 16; m <<= 1) {
            unsigned long long ok = __shfl_xor(key, m, 64);
            float ov2 = __shfl_xor(w2, m, 64);
            unsigned long long lk = (key < ok) ? key : ok;   // losing top1
            float lv2 = ord_f32((unsigned int)(lk >> 32));
            w2 = fmaxf(fmaxf(w2, ov2), lv2);
            key = (key > ok) ? key : ok;                      // ties: smaller c
        }
        if (lm == 0) {
            const int tn = tw + kg * 4 + j;
            float v1m = ord_f32((unsigned int)(key >> 32));
            if (__fsub_rn(v1m, w2) > CERT) {
                wsrow[tn] = key;      // certified: provably exact argmax index
            } else {
                unsigned int p = atomicAdd(lcnt, 1u);
                list[p] = (unsigned int)tn;
            }
        }
    }

    for (int code = t; code < 1024; code += 512)
        cbm[(size_t)code * 512 + blockIdx.x] = ord_f32(cmU[code]);
}

// ---- K2: merged exact rescore (col: blocks 0..1023; row: 1024..2047) ----
// Bodies verbatim from the 259.4us-validated round-12 code.
__global__ __launch_bounds__(256) void k_rescore(
    const float* __restrict__ z, const float* __restrict__ emb,
    const float* __restrict__ zn2, const float* __restrict__ en2,
    const float* __restrict__ cbm,
    const unsigned int* __restrict__ list, const unsigned int* __restrict__ lcnt,
    unsigned long long* __restrict__ wscol,
    unsigned long long* __restrict__ wsrow) {
    const int t = threadIdx.x;
    if (blockIdx.x < 1024) {
        // -- column rescore: block per code --
        const int k = blockIdx.x;
        __shared__ float red[256];
        __shared__ int   hlist[512];
        __shared__ int   hcnt;
        float a  = cbm[(size_t)k * 512 + t];
        float b2 = cbm[(size_t)k * 512 + 256 + t];
        red[t] = fmaxf(a, b2);
        if (t == 0) hcnt = 0;
        __syncthreads();
        for (int st = 128; st; st >>= 1) {
            if (t < st) red[t] = fmaxf(red[t], red[t + st]);
            __syncthreads();
        }
        const float thr = red[0] - MARGIN;
        if (a >= thr)  { int p = atomicAdd(&hcnt, 1); hlist[p] = t; }
        if (b2 >= thr) { int p = atomicAdd(&hcnt, 1); hlist[p] = t + 256; }
        __syncthreads();
        const int hc = hcnt;
        const float en2k = en2[k];
        const float4* ek = reinterpret_cast<const float4*>(emb + (size_t)k * 64);

        for (int h = 0; h < hc; ++h) {
            const int g = hlist[h];
            if (t < 128) {
                const int n = g * 128 + t;
                const int b = n >> 12, hw = n & 4095;
                const float* zp = z + (size_t)b * 262144 + hw;
                float c0 = 0.f, c1 = 0.f, c2 = 0.f, c3 = 0.f;
#pragma unroll
                for (int j = 0; j < 16; ++j) {
                    float4 e = ek[j];
                    c0 = fmaf(e.x, zp[(size_t)(4 * j + 0) * 4096], c0);
                    c1 = fmaf(e.y, zp[(size_t)(4 * j + 1) * 4096], c1);
                    c2 = fmaf(e.z, zp[(size_t)(4 * j + 2) * 4096], c2);
                    c3 = fmaf(e.w, zp[(size_t)(4 * j + 3) * 4096], c3);
                }
                float dot = (c0 + c1) + (c2 + c3);
                float d = __fadd_rn(__fsub_rn(-zn2[n], en2k), 2.0f * dot);
                unsigned long long key =
                    ((unsigned long long)f32_ord(d) << 32) |
                    (unsigned long long)(unsigned int)(~(unsigned int)n);
#pragma unroll
                for (int m = 1; m < 64; m <<= 1) {
                    unsigned long long o = __shfl_xor(key, m, 64);
                    if (o > key) key = o;    // ties: larger key = smaller n
                }
                if ((t & 63) == 0) atomicMax(&wscol[k], key);
            }
        }
    } else {
        // -- row rescore for uncertified tokens --
        const int bid2 = blockIdx.x - 1024;
        const int k0 = (bid2 >> 6) * 64;     // 16 partitions of 64 codes
        const unsigned int cnt = *lcnt;
        const float4* E4 = reinterpret_cast<const float4*>(emb);
        for (unsigned int i = (unsigned int)(bid2 & 63) * 256 + t; i < cnt;
             i += 64 * 256) {
            const int n = (int)list[i];
            const int b = n >> 12, hw = n & 4095;
            const float* zp = z + (size_t)b * 262144 + hw;
            const float nz = -zn2[n];
            unsigned long long best = 0ull;
            for (int kk = 0; kk < 64; ++kk) {
                const int k = k0 + kk;               // wave-uniform -> s_load
                const float4* ek = E4 + (size_t)k * 16;
                float c0 = 0.f, c1 = 0.f, c2 = 0.f, c3 = 0.f;
#pragma unroll
                for (int j = 0; j < 16; ++j) {
                    float4 e = ek[j];
                    c0 = fmaf(e.x, zp[(size_t)(4 * j + 0) * 4096], c0);
                    c1 = fmaf(e.y, zp[(size_t)(4 * j + 1) * 4096], c1);
                    c2 = fmaf(e.z, zp[(size_t)(4 * j + 2) * 4096], c2);
                    c3 = fmaf(e.w, zp[(size_t)(4 * j + 3) * 4096], c3);
                }
                float dot = (c0 + c1) + (c2 + c3);
                float d = __fadd_rn(__fsub_rn(nz, en2[k]), 2.0f * dot);
                unsigned long long key =
                    ((unsigned long long)f32_ord(d) << 32) |
                    (unsigned long long)(unsigned int)(~(unsigned int)k);
                if (key > best) best = key;   // ties: larger key = smaller k
            }
            atomicMax(&wsrow[n], best);
        }
    }
}

// ---- K3: per-token outputs, 4-way channel split (1024 blocks) ----
__global__ __launch_bounds__(256) void k_tokens(
    const float* __restrict__ z, const float* __restrict__ emb,
    const unsigned long long* __restrict__ wsrow,
    unsigned int* __restrict__ counts, double* __restrict__ loss_acc,
    float* __restrict__ out_zq, float* __restrict__ out_idx) {
    const int t    = threadIdx.x;
    const int lane = t & 63;
    const int q    = t >> 6;
    const int n    = blockIdx.x * 64 + lane;
    const int b    = n >> 12;
    const int hw   = n & 4095;

    unsigned long long key = wsrow[n];
    int idx = (int)(~(unsigned int)(key & 0xFFFFFFFFull));
    if (q == 0) {
        out_idx[n] = (float)idx;
        atomicAdd(&counts[idx], 1u);
    }

    const float* zp = z + (size_t)b * 262144 + hw;
    float*       op = out_zq + (size_t)b * 262144 + hw;
    const float* ep = emb + (size_t)idx * 64;

    double ls = 0.0;
#pragma unroll
    for (int c = q * 16; c < q * 16 + 16; ++c) {
        float zc   = zp[(size_t)c * 4096];
        float eq   = ep[c];
        float diff = __fsub_rn(eq, zc);              // fl(z_q - zc)
        float sq   = __fmul_rn(diff, diff);
        ls += (double)sq;
        op[(size_t)c * 4096] = __fadd_rn(zc, diff);  // zc + fl(z_q - zc)
    }

    __shared__ double sred[256];
    sred[q * 64 + lane] = ls;
    __syncthreads();
    if (t < 64) {
        sred[t] = (sred[t] + sred[64 + t]) + (sred[128 + t] + sred[192 + t]);
    }
    __syncthreads();
    for (int st = 32; st; st >>= 1) {
        if (t < st) sred[t] += sred[t + st];
        __syncthreads();
    }
    if (t == 0) atomicAdd(loss_acc, sred[0]);
}

// ---- K4: tail — new embedding + scalars (unchanged) ----
__global__ __launch_bounds__(1024) void k_tail(
    const float* __restrict__ z, const float* __restrict__ emb,
    const float* __restrict__ embed_prob,
    const unsigned long long* __restrict__ wscol,
    const unsigned int* __restrict__ counts,
    const double* __restrict__ loss_acc,
    float* __restrict__ out_newemb, float* __restrict__ out_loss,
    float* __restrict__ out_perp, float* __restrict__ out_prob) {
    const int k = blockIdx.x * 16 + (threadIdx.x >> 6);
    const int c = threadIdx.x & 63;

    float avg  = (float)counts[k] * (1.0f / 65536.0f);
    float pnew = __fadd_rn(__fmul_rn(embed_prob[k], 0.99f),
                           __fmul_rn(0.01f, avg));
    float tt = __fdiv_rn(__fmul_rn(__fmul_rn(pnew, 1024.0f), 10.0f), 0.01f);
    float dk = expf(__fsub_rn(-tt, 1e-3f));
    float omd = __fsub_rn(1.0f, dk);

    unsigned long long ck = wscol[k];
    int cn  = (int)(~(unsigned int)(ck & 0xFFFFFFFFull));
    int cb  = cn >> 12;
    int chw = cn & 4095;

    float rf = z[(size_t)cb * 262144 + (size_t)c * 4096 + chw];
    float e  = emb[(size_t)k * 64 + c];
    out_newemb[(size_t)k * 64 + c] =
        __fadd_rn(__fmul_rn(e, omd), __fmul_rn(rf, dk));

    if (blockIdx.x == 0) {
        const int q = threadIdx.x;

        float avg2  = (float)counts[q] * (1.0f / 65536.0f);
        float pnew2 = __fadd_rn(__fmul_rn(embed_prob[q], 0.99f),
                                __fmul_rn(0.01f, avg2));
        out_prob[q] = pnew2;

        float term = __fmul_rn(avg2, logf(__fadd_rn(avg2, 1e-10f)));
        __shared__ double red[1024];
        red[q] = (double)term;
        __syncthreads();
        for (int st = 512; st; st >>= 1) {
            if (q < st) red[q] += red[q + st];
            __syncthreads();
        }
        if (q == 0) {
            float s32 = (float)red[0];
            out_perp[0] = expf(-s32);
            double lm = loss_acc[0] / 4194304.0;
            float  m  = (float)lm;
            out_loss[0] = __fadd_rn(__fmul_rn(0.25f, m), m);  // BETA*m + m
        }
    }
}

extern "C" void kernel_launch(void* const* d_in, const int* in_sizes, int n_in,
                              void* d_out, int out_size, void* d_ws, size_t ws_size,
                              hipStream_t stream) {
    const float* z    = (const float*)d_in[0];   // 16*64*64*64
    const float* emb  = (const float*)d_in[1];   // 1024*64
    const float* prob = (const float*)d_in[2];   // 1024

    float* out        = (float*)d_out;
    float* out_zq     = out;                 // 4194304 floats
    float* out_loss   = out + 4194304;
    float* out_perp   = out + 4194305;
    float* out_newemb = out + 4194306;
    float* out_prob   = out + 4259842;
    float* out_idx    = out + 4260866;

    char* ws = (char*)d_ws;
    unsigned long long* wsrow = (unsigned long long*)(ws + WS_ROW);
    unsigned long long* wscol = (unsigned long long*)(ws + WS_COL);
    unsigned int*       cnts  = (unsigned int*)(ws + WS_CNT);
    double*             lacc  = (double*)(ws + WS_LOSS);
    float*              en2   = (float*)(ws + WS_EN2);
    unsigned int*       lcnt  = (unsigned int*)(ws + WS_LCNT);
    float*              zn2   = (float*)(ws + WS_ZN2);
    unsigned short*     ebh   = (unsigned short*)(ws + WS_EBH);
    unsigned short*     ebl   = (unsigned short*)(ws + WS_EBL);
    unsigned int*       list  = (unsigned int*)(ws + WS_LIST);
    float*              cbm   = (float*)(ws + WS_CBM);

    hipMemsetAsync(d_ws, 0, WS_ZERO, stream);

    hipLaunchKernelGGL(k_prep, dim3(4), dim3(256), 0, stream,
                       emb, en2, (unsigned int*)ebh, (unsigned int*)ebl);
    hipLaunchKernelGGL(k_mfma, dim3(512), dim3(512), 0, stream,
                       z, ebh, ebl, zn2, en2, cbm, wsrow, lcnt, list);
    hipLaunchKernelGGL(k_rescore, dim3(2048), dim3(256), 0, stream,
                       z, emb, zn2, en2, cbm, list, lcnt, wscol, wsrow);
    hipLaunchKernelGGL(k_tokens, dim3(1024), dim3(256), 0, stream,
                       z, emb, wsrow, cnts, lacc, out_zq, out_idx);
    hipLaunchKernelGGL(k_tail, dim3(64), dim3(1024), 0, stream,
                       z, emb, prob, wscol, cnts, lacc,
                       out_newemb, out_loss, out_perp, out_prob);
}